// Round 4
// baseline (957.847 us; speedup 1.0000x reference)
//
#include <hip/hip_runtime.h>
#include <math.h>

// Problem constants: B=4, N=1024, E=1024, H=16, D=64, NUM_BUCKETS=320, MAX_DISTANCE=800
#define BB 4
#define NN 1024
#define EE 1024
#define HH 16
#define DD 64

// ---------------------------------------------------------------------------
// 1) Relative-position bias table: bucket depends only on rel = j - i
//    biasT[h][rel + 1023]  (stride 2048), rel in [-1023, 1023]
// ---------------------------------------------------------------------------
__global__ void bias_table_kernel(const float* __restrict__ rel_embed, // (320,16)
                                  float* __restrict__ biasT)           // (16,2048)
{
    int idx = blockIdx.x * 256 + threadIdx.x;
    if (idx >= 2 * NN - 1) return;
    int rel = idx - (NN - 1);
    int bucket = (rel > 0) ? 160 : 0;
    int ra = rel < 0 ? -rel : rel;
    int v;
    if (ra < 80) {
        v = ra;
    } else {
        // match f32 op order of reference: log(ra/80)/log(10)*80, then +80, trunc
        float lg = logf((float)ra / 80.0f) / 2.302585092994046f * 80.0f;
        v = (int)(80.0f + lg);
        if (v > 159) v = 159;
    }
    bucket += v;
#pragma unroll
    for (int h = 0; h < HH; ++h)
        biasT[h * 2048 + idx] = rel_embed[bucket * HH + h];
}

// ---------------------------------------------------------------------------
// 2) Gate: proj = ghs @ gru_W.T + gru_b ; reshape(...,2,4).sum(-1); sigmoid
//    Equivalent: two dot products with column-summed weights.
//    gate_out[b][h][n] = ga*(gb*gc[h]-1)+2
// ---------------------------------------------------------------------------
__global__ __launch_bounds__(256) void gate_kernel(
    const float* __restrict__ hs,  // (B,N,E)
    const float* __restrict__ gW,  // (8,64)
    const float* __restrict__ gb,  // (8,)
    const float* __restrict__ gc,  // (1,H,1,1) -> 16
    float* __restrict__ gate_out)  // (B,H,N)
{
    __shared__ float wA[64], wB[64], bsum[2];
    int t = threadIdx.x;
    if (t < 64) {
        wA[t] = gW[0 * 64 + t] + gW[1 * 64 + t] + gW[2 * 64 + t] + gW[3 * 64 + t];
        wB[t] = gW[4 * 64 + t] + gW[5 * 64 + t] + gW[6 * 64 + t] + gW[7 * 64 + t];
    }
    if (t == 0) bsum[0] = gb[0] + gb[1] + gb[2] + gb[3];
    if (t == 1) bsum[1] = gb[4] + gb[5] + gb[6] + gb[7];
    __syncthreads();
    int idx = blockIdx.x * 256 + t;       // idx = (b*16+h)*1024 + n
    int n = idx & (NN - 1);
    int h = (idx >> 10) & (HH - 1);
    int b = idx >> 14;
    const float* hp = hs + ((size_t)(b * NN + n)) * EE + h * DD;
    float sA = bsum[0], sB = bsum[1];
#pragma unroll 8
    for (int d = 0; d < 64; ++d) {
        float x = hp[d];
        sA = fmaf(x, wA[d], sA);
        sB = fmaf(x, wB[d], sB);
    }
    float ga = 1.0f / (1.0f + __expf(-sA));
    float gbv = 1.0f / (1.0f + __expf(-sB));
    gate_out[idx] = ga * (gbv * gc[h] - 1.0f) + 2.0f;
}

// ---------------------------------------------------------------------------
// 3) GEMM (NT): C[m][e] = sum_k A[m][k] * W[e][k] + bias[e]
//    M=4096, N=1024, K=1024. Block 256 thr, tile 64x64, BK=32, 4x4/thread.
//    qkv=1: scatter output to (B,H,N,D); qkv=0: linear (M,1024).
// ---------------------------------------------------------------------------
__global__ __launch_bounds__(256) void gemm_nt_kernel(
    const float* __restrict__ A, const float* __restrict__ W,
    const float* __restrict__ bias, float* __restrict__ Cout, int qkv)
{
    __shared__ float As[32][68];  // [k][m]
    __shared__ float Bs[32][68];  // [k][n]
    const int t = threadIdx.x;
    const int tr = t >> 4, tc = t & 15;
    const int m0 = blockIdx.y * 64, n0 = blockIdx.x * 64;
    const int lr = t >> 3;            // 0..31
    const int lk = (t & 7) << 2;      // 0..28
    const float* Ag0 = A + (size_t)(m0 + lr) * 1024 + lk;
    const float* Ag1 = Ag0 + (size_t)32 * 1024;
    const float* Wg0 = W + (size_t)(n0 + lr) * 1024 + lk;
    const float* Wg1 = Wg0 + (size_t)32 * 1024;
    float c[4][4] = {};
    for (int k0 = 0; k0 < 1024; k0 += 32) {
        float4 a0 = *(const float4*)(Ag0 + k0);
        float4 a1 = *(const float4*)(Ag1 + k0);
        float4 w0 = *(const float4*)(Wg0 + k0);
        float4 w1 = *(const float4*)(Wg1 + k0);
        __syncthreads();
        As[lk + 0][lr] = a0.x; As[lk + 1][lr] = a0.y; As[lk + 2][lr] = a0.z; As[lk + 3][lr] = a0.w;
        As[lk + 0][lr + 32] = a1.x; As[lk + 1][lr + 32] = a1.y; As[lk + 2][lr + 32] = a1.z; As[lk + 3][lr + 32] = a1.w;
        Bs[lk + 0][lr] = w0.x; Bs[lk + 1][lr] = w0.y; Bs[lk + 2][lr] = w0.z; Bs[lk + 3][lr] = w0.w;
        Bs[lk + 0][lr + 32] = w1.x; Bs[lk + 1][lr + 32] = w1.y; Bs[lk + 2][lr + 32] = w1.z; Bs[lk + 3][lr + 32] = w1.w;
        __syncthreads();
#pragma unroll
        for (int kk = 0; kk < 32; ++kk) {
            float4 a4 = *(const float4*)&As[kk][tr << 2];
            float4 b4 = *(const float4*)&Bs[kk][tc << 2];
            float a[4] = {a4.x, a4.y, a4.z, a4.w};
            float b[4] = {b4.x, b4.y, b4.z, b4.w};
#pragma unroll
            for (int i = 0; i < 4; ++i)
#pragma unroll
                for (int j = 0; j < 4; ++j)
                    c[i][j] = fmaf(a[i], b[j], c[i][j]);
        }
    }
    const int e0 = n0 + (tc << 2);
    float4 bv = *(const float4*)(bias + e0);
#pragma unroll
    for (int i = 0; i < 4; ++i) {
        int m = m0 + (tr << 2) + i;
        float4 r;
        r.x = c[i][0] + bv.x; r.y = c[i][1] + bv.y; r.z = c[i][2] + bv.z; r.w = c[i][3] + bv.w;
        if (qkv) {
            int b = m >> 10, n = m & 1023;
            int h = e0 >> 6, d = e0 & 63;
            *(float4*)(Cout + (((size_t)(b * HH + h) * NN + n) * DD + d)) = r;
        } else {
            *(float4*)(Cout + (size_t)m * 1024 + e0) = r;
        }
    }
}

// ---------------------------------------------------------------------------
// 4) Flash attention per (b,h), 64 query rows per block, fp32.
//    scores = QK^T * 0.125 + gate[b,h,i] * biasT[h][j-i+1023]; online softmax.
//    Output written directly in (B,N,H*D) layout for the final GEMM.
// ---------------------------------------------------------------------------
__global__ __launch_bounds__(256) void attn_kernel(
    const float* __restrict__ Q,     // (B,H,N,D)
    const float* __restrict__ K,
    const float* __restrict__ V,
    const float* __restrict__ biasT, // (16,2048)
    const float* __restrict__ gate,  // (B,H,N)
    float* __restrict__ Aout)        // (B,N,E)
{
    __shared__ float Qt[64][64];   // [d][r]
    __shared__ float Kt[64][64];   // [d][j]
    __shared__ float Vs[64][68];   // [j][d]
    __shared__ float Pt[64][68];   // [j][r]
    __shared__ float Bh[2048];
    __shared__ float Gs[64];

    const int t = threadIdx.x;
    const int tr = t >> 4, tc = t & 15;
    const int i0 = blockIdx.x * 64;
    const int bh = blockIdx.y;         // b*16 + h
    const int h = bh & 15;
    const float* Qg = Q + (size_t)bh * NN * DD;
    const float* Kg = K + (size_t)bh * NN * DD;
    const float* Vg = V + (size_t)bh * NN * DD;

    for (int x = t; x < 2047; x += 256) Bh[x] = biasT[h * 2048 + x];
    if (t < 64) Gs[t] = gate[(size_t)bh * NN + i0 + t];

#pragma unroll
    for (int rr = 0; rr < 4; ++rr) {
        int r = rr * 16 + tr;
        int d0 = tc << 2;
        float4 qv = *(const float4*)(Qg + (size_t)(i0 + r) * DD + d0);
        Qt[d0 + 0][r] = qv.x; Qt[d0 + 1][r] = qv.y; Qt[d0 + 2][r] = qv.z; Qt[d0 + 3][r] = qv.w;
    }
    __syncthreads();

    float m_run[4], l_run[4], o[4][4];
#pragma unroll
    for (int i = 0; i < 4; ++i) {
        m_run[i] = -INFINITY; l_run[i] = 0.0f;
#pragma unroll
        for (int d = 0; d < 4; ++d) o[i][d] = 0.0f;
    }
    float gr[4];
#pragma unroll
    for (int i = 0; i < 4; ++i) gr[i] = Gs[(tr << 2) + i];

    for (int jt = 0; jt < 16; ++jt) {
        const int j0 = jt * 64;
        __syncthreads();  // protect Kt/Vs/Pt from previous iteration readers
#pragma unroll
        for (int rr = 0; rr < 4; ++rr) {
            int r = rr * 16 + tr;
            int d0 = tc << 2;
            float4 kv = *(const float4*)(Kg + (size_t)(j0 + r) * DD + d0);
            Kt[d0 + 0][r] = kv.x; Kt[d0 + 1][r] = kv.y; Kt[d0 + 2][r] = kv.z; Kt[d0 + 3][r] = kv.w;
            float4 vv = *(const float4*)(Vg + (size_t)(j0 + r) * DD + d0);
            *(float4*)&Vs[r][d0] = vv;
        }
        __syncthreads();

        // S = Q K^T  (4 rows x 4 cols per thread)
        float s[4][4] = {};
#pragma unroll 8
        for (int kd = 0; kd < 64; ++kd) {
            float4 a4 = *(const float4*)&Qt[kd][tr << 2];
            float4 b4 = *(const float4*)&Kt[kd][tc << 2];
            float a[4] = {a4.x, a4.y, a4.z, a4.w};
            float b[4] = {b4.x, b4.y, b4.z, b4.w};
#pragma unroll
            for (int i = 0; i < 4; ++i)
#pragma unroll
                for (int j = 0; j < 4; ++j)
                    s[i][j] = fmaf(a[i], b[j], s[i][j]);
        }
        // scale + gated bias
#pragma unroll
        for (int i = 0; i < 4; ++i) {
            int ig = i0 + (tr << 2) + i;
#pragma unroll
            for (int j = 0; j < 4; ++j) {
                int jg = j0 + (tc << 2) + j;
                s[i][j] = fmaf(s[i][j], 0.125f, gr[i] * Bh[jg - ig + 1023]);
            }
        }
        // online softmax (row groups of 16 lanes: tc)
        float pnew[4][4];
#pragma unroll
        for (int i = 0; i < 4; ++i) {
            float mx = fmaxf(fmaxf(s[i][0], s[i][1]), fmaxf(s[i][2], s[i][3]));
            mx = fmaxf(mx, __shfl_xor(mx, 1));
            mx = fmaxf(mx, __shfl_xor(mx, 2));
            mx = fmaxf(mx, __shfl_xor(mx, 4));
            mx = fmaxf(mx, __shfl_xor(mx, 8));
            float mnew = fmaxf(m_run[i], mx);
            float alpha = __expf(m_run[i] - mnew);
            float rs = 0.0f;
#pragma unroll
            for (int j = 0; j < 4; ++j) {
                float p = __expf(s[i][j] - mnew);
                pnew[i][j] = p;
                rs += p;
            }
            rs += __shfl_xor(rs, 1);
            rs += __shfl_xor(rs, 2);
            rs += __shfl_xor(rs, 4);
            rs += __shfl_xor(rs, 8);
            l_run[i] = l_run[i] * alpha + rs;
            m_run[i] = mnew;
#pragma unroll
            for (int d = 0; d < 4; ++d) o[i][d] *= alpha;
        }
        // write P transposed: Pt[j][r]
#pragma unroll
        for (int j = 0; j < 4; ++j) {
            float4 pv;
            pv.x = pnew[0][j]; pv.y = pnew[1][j]; pv.z = pnew[2][j]; pv.w = pnew[3][j];
            *(float4*)&Pt[(tc << 2) + j][tr << 2] = pv;
        }
        __syncthreads();
        // O += P V
#pragma unroll 8
        for (int j = 0; j < 64; ++j) {
            float4 p4 = *(const float4*)&Pt[j][tr << 2];
            float4 v4 = *(const float4*)&Vs[j][tc << 2];
            float p[4] = {p4.x, p4.y, p4.z, p4.w};
            float v[4] = {v4.x, v4.y, v4.z, v4.w};
#pragma unroll
            for (int i = 0; i < 4; ++i)
#pragma unroll
                for (int d = 0; d < 4; ++d)
                    o[i][d] = fmaf(p[i], v[d], o[i][d]);
        }
    }
    // epilogue: normalize, write to (B,N,H*D)
    const int b = bh >> 4;
#pragma unroll
    for (int i = 0; i < 4; ++i) {
        float inv = 1.0f / l_run[i];
        int n = i0 + (tr << 2) + i;
        float4 r;
        r.x = o[i][0] * inv; r.y = o[i][1] * inv; r.z = o[i][2] * inv; r.w = o[i][3] * inv;
        *(float4*)(Aout + ((size_t)(b * NN + n) * EE) + h * DD + (tc << 2)) = r;
    }
}

// ---------------------------------------------------------------------------
// launch
// ---------------------------------------------------------------------------
extern "C" void kernel_launch(void* const* d_in, const int* in_sizes, int n_in,
                              void* d_out, int out_size, void* d_ws, size_t ws_size,
                              hipStream_t stream) {
    (void)in_sizes; (void)n_in; (void)out_size; (void)ws_size;
    const float* hs = (const float*)d_in[0];
    const float* Wq = (const float*)d_in[1];
    const float* bq = (const float*)d_in[2];
    const float* Wk = (const float*)d_in[3];
    const float* bk = (const float*)d_in[4];
    const float* Wv = (const float*)d_in[5];
    const float* bv = (const float*)d_in[6];
    const float* Wo = (const float*)d_in[7];
    const float* bo = (const float*)d_in[8];
    const float* gc = (const float*)d_in[9];
    const float* gW = (const float*)d_in[10];
    const float* gb = (const float*)d_in[11];
    const float* re = (const float*)d_in[12];

    float* ws = (float*)d_ws;
    float* Qb   = ws;                       // 4*16*1024*64 = 4194304 floats
    float* Kb   = ws + 4194304;
    float* Vb   = ws + 8388608;
    float* AO   = ws + 12582912;            // (4096,1024)
    float* bT   = ws + 16777216;            // 16*2048
    float* gate = ws + 16777216 + 32768;    // 4*16*1024

    float* out = (float*)d_out;

    hipLaunchKernelGGL(bias_table_kernel, dim3(8), dim3(256), 0, stream, re, bT);
    hipLaunchKernelGGL(gate_kernel, dim3(256), dim3(256), 0, stream, hs, gW, gb, gc, gate);
    dim3 gg(16, 64);  // (n-tiles, m-tiles)
    hipLaunchKernelGGL(gemm_nt_kernel, gg, dim3(256), 0, stream, hs, Wq, bq, Qb, 1);
    hipLaunchKernelGGL(gemm_nt_kernel, gg, dim3(256), 0, stream, hs, Wk, bk, Kb, 1);
    hipLaunchKernelGGL(gemm_nt_kernel, gg, dim3(256), 0, stream, hs, Wv, bv, Vb, 1);
    hipLaunchKernelGGL(attn_kernel, dim3(16, 64), dim3(256), 0, stream, Qb, Kb, Vb, bT, gate, AO);
    hipLaunchKernelGGL(gemm_nt_kernel, gg, dim3(256), 0, stream, AO, Wo, bo, out, 0);
}